// Round 8
// baseline (48853.287 us; speedup 1.0000x reference)
//
#include <hip/hip_runtime.h>
#include <math.h>

#define L_SEQ 8192
#define I_DIM 256
#define H_DIM 2048
#define NWG0  64          // layer-0: 64 WGs x 32 rows (4 rows/wave, col-block per lane)
#define NWG1  128         // layer-1: 128 WGs x 16 rows (2 rows/wave)
#define NWG   (NWG0 + NWG1)
#define TPB   512

// ws: [0] runctr | [256..1024) bslots | [4096) h0 ring 8*2048 f32 | [+64K) h1 ring
//
// Protocol = round-4's tagged dataflow (proven passing, rounds 4-7): published
// value = h + ctr(step), ctr = 4+8*((step>>3)&1), ring depth 8, valid iff
// |v-ctr|<=1; slots re-inited per run; poison(0xAA)/0.0 never match; start
// barrier on monotone runctr. Throttle every 4th step (L0 checks all L1 WGs
// published h1_{s-4}); safety margins as proven in round 7's header.
//
// THE FIX THIS ROUND: explicit occupancy pin. Empirically the allocator capped
// VGPRs at 128 in every prior round (observed 88/92/128/96/104, round 5 exactly
// at the cap) => the 144-reg weight set always spilled to scratch, and the
// spill stream through LLC (~50 MB/step) was the invariant ~4us/step floor.
// amdgpu_waves_per_eu(2,2) makes max occupancy 2 waves/SIMD a *known ceiling*,
// so RA can use up to 256 VGPRs: L0 ~205, L1 ~180 -> no spill.
// Weights stay as NAMED float4 scalars (no arrays -> no SROA-to-scratch),
// loaded via asm-opaque ld4 (no remat).

__device__ __forceinline__ void cstore1(float* p, float v) {
  asm volatile("global_store_dword %0, %1, off sc0 sc1" :: "v"(p), "v"(v) : "memory");
}
__device__ __forceinline__ void cstoreu(unsigned* p, unsigned v) {
  asm volatile("global_store_dword %0, %1, off sc0 sc1" :: "v"(p), "v"(v) : "memory");
}
__device__ __forceinline__ float cload1(const float* p) {
  float v;
  asm volatile("global_load_dword %0, %1, off sc0 sc1\n\ts_waitcnt vmcnt(0)"
               : "=v"(v) : "v"(p) : "memory");
  return v;
}
__device__ __forceinline__ unsigned cloadu(const unsigned* p) {
  unsigned v;
  asm volatile("global_load_dword %0, %1, off sc0 sc1\n\ts_waitcnt vmcnt(0)"
               : "=v"(v) : "v"(p) : "memory");
  return v;
}
__device__ __forceinline__ float4 cload4(const float* p) {
  float4 v;
  asm volatile("global_load_dwordx4 %0, %1, off sc0 sc1\n\ts_waitcnt vmcnt(0)"
               : "=v"(v) : "v"(p) : "memory");
  return v;
}
__device__ __forceinline__ void cload4x2(const float* p0, const float* p1, float4& a, float4& b) {
  asm volatile("global_load_dwordx4 %0, %2, off sc0 sc1\n\t"
               "global_load_dwordx4 %1, %3, off sc0 sc1\n\t"
               "s_waitcnt vmcnt(0)"
               : "=&v"(a), "=&v"(b) : "v"(p0), "v"(p1) : "memory");
}
__device__ __forceinline__ float4 ld4(const float* p) {   // weight load, opaque
  float4 v;
  asm volatile("global_load_dwordx4 %0, %1, off\n\ts_waitcnt vmcnt(0)"
               : "=v"(v) : "v"(p) : "memory");
  return v;
}
__device__ __forceinline__ float tagc(int step) {
  return 4.f + 8.f * (float)((step >> 3) & 1);
}
__device__ __forceinline__ bool ok4(float4 v, float c) {
  return __builtin_fabsf(v.x - c) <= 1.f && __builtin_fabsf(v.y - c) <= 1.f &&
         __builtin_fabsf(v.z - c) <= 1.f && __builtin_fabsf(v.w - c) <= 1.f;
}
__device__ __forceinline__ float4 poll4(const float* p, float c) {
  for (;;) {
    float4 v = cload4(p);
    if (ok4(v, c)) return make_float4(v.x - c, v.y - c, v.z - c, v.w - c);
  }
}
__device__ __forceinline__ void poll4x2(const float* p0, float c0,
                                        const float* p1, float c1,
                                        float4& a, float4& b) {
  for (;;) {
    float4 u, v;
    cload4x2(p0, p1, u, v);
    if (ok4(u, c0) && ok4(v, c1)) {
      a = make_float4(u.x - c0, u.y - c0, u.z - c0, u.w - c0);
      b = make_float4(v.x - c1, v.y - c1, v.z - c1, v.w - c1);
      return;
    }
  }
}
__device__ __forceinline__ float tanh_fast(float v) {   // exact identity
  float e = __expf(2.f * v);
  return 1.f - 2.f / (e + 1.f);
}
__device__ __forceinline__ void start_barrier(unsigned* bslots, int wg, int tid, unsigned value) {
  __syncthreads();
  if (tid == 0) cstoreu(&bslots[wg], value);
  if (tid < NWG) {
    while ((int)(cloadu(&bslots[tid]) - value) < 0) __builtin_amdgcn_s_sleep(1);
  }
  __syncthreads();
}

#define K8(M) M(0) M(1) M(2) M(3) M(4) M(5) M(6) M(7)
#define MAC4(A, W, H) \
  A.x = __builtin_fmaf((W).x, (H).x, A.x); A.y = __builtin_fmaf((W).y, (H).y, A.y); \
  A.z = __builtin_fmaf((W).z, (H).z, A.z); A.w = __builtin_fmaf((W).w, (H).w, A.w);

__global__ void
__attribute__((amdgpu_flat_work_group_size(TPB, TPB), amdgpu_waves_per_eu(2, 2)))
rnn2_pinned(const float* __restrict__ x,
            const float* __restrict__ Wih0, const float* __restrict__ Whh0,
            const float* __restrict__ bih0, const float* __restrict__ bhh0,
            const float* __restrict__ Wih1, const float* __restrict__ Whh1,
            const float* __restrict__ bih1, const float* __restrict__ bhh1,
            const float* __restrict__ Wfc,  const float* __restrict__ bfc,
            float* __restrict__ out,
            unsigned* __restrict__ runctr, unsigned* __restrict__ bslots,
            float* __restrict__ h0s, float* __restrict__ h1s)
{
  const int wg   = blockIdx.x;
  const int tid  = threadIdx.x;
  const int lane = tid & 63;
  const int wv   = tid >> 6;

  __shared__ float4 h0l[2][576];
  __shared__ float4 h1l[2][576];

  const unsigned runbase = cloadu(runctr);

  if (wg < NWG0) {
    // ===== layer 0: rows r0..r0+3 = wg*32 + wv*4 ; lane owns cols [32l,32l+32) =====
    const int r0 = wg * 32 + wv * 4;
    #define DCL0(k) float4 wa0_##k, wa1_##k, wa2_##k, wa3_##k;
    K8(DCL0)
    float4 wi0, wi1, wi2, wi3;
    {
      const float* b0 = Whh0 + (size_t)r0 * H_DIM + lane * 32;
      const float* b1 = b0 + H_DIM;
      const float* b2 = b0 + 2 * H_DIM;
      const float* b3 = b0 + 3 * H_DIM;
      #define LDW0(k) wa0_##k = ld4(b0 + 4*k); wa1_##k = ld4(b1 + 4*k); \
                      wa2_##k = ld4(b2 + 4*k); wa3_##k = ld4(b3 + 4*k);
      K8(LDW0)
      const float* bi = Wih0 + (size_t)r0 * I_DIM + lane * 4;
      wi0 = ld4(bi); wi1 = ld4(bi + I_DIM); wi2 = ld4(bi + 2 * I_DIM); wi3 = ld4(bi + 3 * I_DIM);
    }
    const float bs0 = bih0[r0] + bhh0[r0];
    const float bs1 = bih0[r0 + 1] + bhh0[r0 + 1];
    const float bs2 = bih0[r0 + 2] + bhh0[r0 + 2];
    const float bs3 = bih0[r0 + 3] + bhh0[r0 + 3];

    if (tid < 256) {   // re-init 8 ring slots of owned rows: slot0 = tagged h0_0
      int sl = tid >> 5; int r = wg * 32 + (tid & 31);
      cstore1(&h0s[sl * H_DIM + r], (sl == 0) ? 4.f : 0.f);
    }
    start_barrier(bslots, wg, tid, runbase + 1);

    for (int s = 1; s <= L_SEQ; ++s) {
      const int P = s & 1;
      if ((s & 3) == 0 && s > 4 && tid < NWG1) {   // throttle: all L1 >= s-4
        const float c = tagc(s - 4);
        const float* tp = h1s + ((s - 4) & 7) * H_DIM + tid * 16;
        while (__builtin_fabsf(cload1(tp) - c) > 1.f) {}
      }
      // x_t column block for this lane's 4 Wih cols: one cached float4
      float4 hx = ((const float4*)x)[(size_t)(s - 1) * 64 + lane];
      float4 hv = poll4(h0s + ((s - 1) & 7) * H_DIM + (tid << 2), tagc(s - 1));
      h0l[P][tid + (tid >> 3)] = hv;
      __syncthreads();

      float4 p0 = {0,0,0,0}, p1 = {0,0,0,0}, p2 = {0,0,0,0}, p3 = {0,0,0,0};
      #define F0(k) { float4 h = h0l[P][9*lane + k]; \
                      MAC4(p0, wa0_##k, h) MAC4(p1, wa1_##k, h) \
                      MAC4(p2, wa2_##k, h) MAC4(p3, wa3_##k, h) }
      K8(F0)
      MAC4(p0, wi0, hx) MAC4(p1, wi1, hx) MAC4(p2, wi2, hx) MAC4(p3, wi3, hx)
      float s0 = (p0.x + p0.y) + (p0.z + p0.w);
      float s1 = (p1.x + p1.y) + (p1.z + p1.w);
      float s2 = (p2.x + p2.y) + (p2.z + p2.w);
      float s3 = (p3.x + p3.y) + (p3.z + p3.w);
      #pragma unroll
      for (int m = 1; m < 64; m <<= 1) {
        s0 += __shfl_xor(s0, m); s1 += __shfl_xor(s1, m);
        s2 += __shfl_xor(s2, m); s3 += __shfl_xor(s3, m);
      }
      if (lane == 0) {
        const float ct = tagc(s);
        float* dst = h0s + (s & 7) * H_DIM + r0;
        cstore1(dst + 0, tanh_fast(s0 + bs0) + ct);
        cstore1(dst + 1, tanh_fast(s1 + bs1) + ct);
        cstore1(dst + 2, tanh_fast(s2 + bs2) + ct);
        cstore1(dst + 3, tanh_fast(s3 + bs3) + ct);
      }
    }

    if (wg == 0) {
      // FC: sigmoid(h1_8192 . Wfc + bfc); slot 8192&7 = 0, ctr 4
      float4 hv = poll4(h1s + (tid << 2), tagc(L_SEQ));
      float4 wf = ((const float4*)Wfc)[tid];
      float pz = hv.x * wf.x + hv.y * wf.y + hv.z * wf.z + hv.w * wf.w;
      #pragma unroll
      for (int m = 1; m < 64; m <<= 1) pz += __shfl_xor(pz, m);
      __syncthreads();
      float* red = (float*)&h0l[0][0];
      if (lane == 0) red[wv] = pz;
      __syncthreads();
      if (tid == 0) {
        float z = bfc[0];
        #pragma unroll
        for (int w = 0; w < 8; ++w) z += red[w];
        out[0] = 1.f / (1.f + __expf(-z));
        cstoreu(runctr, runbase + 1);
      }
    }
  } else {
    // ===== layer 1: rows r0, r0+1 = (wg-NWG0)*16 + wv*2 ; lane owns cols [32l,32l+32) =====
    const int wgl = wg - NWG0;
    const int r0  = wgl * 16 + wv * 2;
    #define DCL1(k) float4 ia_##k, ib_##k, ha_##k, hb_##k;
    K8(DCL1)
    {
      const float* i0 = Wih1 + (size_t)r0 * H_DIM + lane * 32;
      const float* i1 = i0 + H_DIM;
      const float* h0b = Whh1 + (size_t)r0 * H_DIM + lane * 32;
      const float* h1b = h0b + H_DIM;
      #define LDW1(k) ia_##k = ld4(i0 + 4*k); ib_##k = ld4(i1 + 4*k); \
                      ha_##k = ld4(h0b + 4*k); hb_##k = ld4(h1b + 4*k);
      K8(LDW1)
    }
    const float ba = bih1[r0] + bhh1[r0];
    const float bb = bih1[r0 + 1] + bhh1[r0 + 1];

    if (tid < 128) {   // re-init 8 ring slots of owned rows: slot0 = tagged h1_0
      int sl = tid >> 4; int r = wgl * 16 + (tid & 15);
      cstore1(&h1s[sl * H_DIM + r], (sl == 0) ? 4.f : 0.f);
    }
    start_barrier(bslots, wg, tid, runbase + 1);

    for (int t = 1; t <= L_SEQ; ++t) {
      const int P = t & 1;
      float4 a, b;
      poll4x2(h0s + (t & 7) * H_DIM + (tid << 2), tagc(t),
              h1s + ((t - 1) & 7) * H_DIM + (tid << 2), tagc(t - 1), a, b);
      h0l[P][tid + (tid >> 3)] = a;
      h1l[P][tid + (tid >> 3)] = b;
      __syncthreads();

      float4 pa = {0,0,0,0}, pb = {0,0,0,0};
      #define F1(k) { float4 h = h0l[P][9*lane + k]; MAC4(pa, ia_##k, h) MAC4(pb, ib_##k, h) \
                      float4 g = h1l[P][9*lane + k]; MAC4(pa, ha_##k, g) MAC4(pb, hb_##k, g) }
      K8(F1)
      float sa = (pa.x + pa.y) + (pa.z + pa.w);
      float sb = (pb.x + pb.y) + (pb.z + pb.w);
      #pragma unroll
      for (int m = 1; m < 64; m <<= 1) {
        sa += __shfl_xor(sa, m); sb += __shfl_xor(sb, m);
      }
      if (lane == 0) {
        const float ct = tagc(t);
        float* dst = h1s + (t & 7) * H_DIM + r0;
        cstore1(dst + 0, tanh_fast(sa + ba) + ct);
        cstore1(dst + 1, tanh_fast(sb + bb) + ct);
      }
    }
  }
}

extern "C" void kernel_launch(void* const* d_in, const int* in_sizes, int n_in,
                              void* d_out, int out_size, void* d_ws, size_t ws_size,
                              hipStream_t stream) {
  const float* xx   = (const float*)d_in[0];
  const float* Wih0 = (const float*)d_in[1];
  const float* Whh0 = (const float*)d_in[2];
  const float* bih0 = (const float*)d_in[3];
  const float* bhh0 = (const float*)d_in[4];
  const float* Wih1 = (const float*)d_in[5];
  const float* Whh1 = (const float*)d_in[6];
  const float* bih1 = (const float*)d_in[7];
  const float* bhh1 = (const float*)d_in[8];
  const float* Wfc  = (const float*)d_in[9];
  const float* bfc  = (const float*)d_in[10];

  unsigned* runctr = (unsigned*)d_ws;
  unsigned* bslots = (unsigned*)((char*)d_ws + 256);
  float* h0s       = (float*)((char*)d_ws + 4096);
  float* h1s       = (float*)((char*)d_ws + 4096 + 8 * H_DIM * sizeof(float));

  rnn2_pinned<<<dim3(NWG), dim3(TPB), 0, stream>>>(
      xx, Wih0, Whh0, bih0, bhh0, Wih1, Whh1, bih1, bhh1, Wfc, bfc,
      (float*)d_out, runctr, bslots, h0s, h1s);
}

// Round 9
// 46060.727 us; speedup vs baseline: 1.0606x; 1.0606x over previous
//
#include <hip/hip_runtime.h>
#include <math.h>

#define L_SEQ 8192
#define I_DIM 256
#define H_DIM 2048
#define NWG0  64          // layer-0: 64 WGs x 32 rows (16 thr/row)
#define NWG1  128         // layer-1: 128 WGs x 16 rows (32 thr/row)
#define NWG   (NWG0 + NWG1)
#define TPB   512

// ws (bytes): [0] runctr | [256..1024) bslots | [4096) h0 ring 8*1024 u32 | [36864) h1 ring
//
// q15-packed tagged dataflow. Each u32 granule-word = two h values:
//   lo16 = even row, hi16 = odd row. Each u16 = (q14 << 2) | tag2 where
//   q14 = clamp(round(h*8192), -8192, 8191)  (quantum 1.2e-4),
//   lo-half tag2 = step&3, hi-half tag2 = (step>>2)&3  -> 4-bit tag = step&15.
// Ring depth 8; slot k users are steps ≡ k (mod 8) -> tags {k, k+8} mod 16
// distinguish 8-stale data. 16-stale is unreachable: the producer drained
// (vmcnt0 in its own polls) the (t-9) store before publishing later steps, so
// a consumer can only observe t-1 or t-9 at slot (t-1)&7, never t-17.
// Init (per run, before start barrier): slot 0 = step-0 encoding of h=0
// (u32 0x0), slots k=1..7 = tag byte T=k+7 (never ≡ k or k+8 mod 16) with
// zero magnitude -> 0xAA poison and stale data never false-validate.
// Throttle: every 4th step s, L0 verifies each L1 WG's sentinel u32 of slot
// (s-4)&7 carries tag s-4 => all L1 >= s-4 >= s-7 before overwriting slot s&7.
// Requests/step: L0 64x256 + L1 128x(256+256) = 82K dwordx4 (half of round 4).
// Publishes: L0 one dwordx2 per wave (4 rows), L1 one dword per wave (2 rows).

__device__ __forceinline__ void cstoreu(unsigned* p, unsigned v) {
  asm volatile("global_store_dword %0, %1, off sc0 sc1" :: "v"(p), "v"(v) : "memory");
}
__device__ __forceinline__ void cstore2(unsigned* p, uint2 v) {
  asm volatile("global_store_dwordx2 %0, %1, off sc0 sc1" :: "v"(p), "v"(v) : "memory");
}
__device__ __forceinline__ unsigned cloadu(const unsigned* p) {
  unsigned v;
  asm volatile("global_load_dword %0, %1, off sc0 sc1\n\ts_waitcnt vmcnt(0)"
               : "=v"(v) : "v"(p) : "memory");
  return v;
}
__device__ __forceinline__ uint4 cloadg(const unsigned* p) {
  uint4 v;
  asm volatile("global_load_dwordx4 %0, %1, off sc0 sc1\n\ts_waitcnt vmcnt(0)"
               : "=v"(v) : "v"(p) : "memory");
  return v;
}
__device__ __forceinline__ float4 ld4(const float* p) {   // weight load, opaque
  float4 v;
  asm volatile("global_load_dwordx4 %0, %1, off\n\ts_waitcnt vmcnt(0)"
               : "=v"(v) : "v"(p) : "memory");
  return v;
}
__device__ __forceinline__ unsigned enc16(float h, unsigned tag2) {
  int q = (int)floorf(h * 8192.f + 0.5f);
  q = q < -8192 ? -8192 : (q > 8191 ? 8191 : q);
  return (unsigned)(((q << 2) | (int)tag2) & 0xFFFF);
}
__device__ __forceinline__ float dec16(unsigned u) {
  return (float)((short)(u & 0xFFFFu) >> 2) * (1.f / 8192.f);
}
__device__ __forceinline__ bool okg(uint4 g, unsigned te, unsigned to) {
  unsigned lo = (g.x & 3u) | ((g.y & 3u) << 2) | ((g.z & 3u) << 4) | ((g.w & 3u) << 6);
  unsigned hi = ((g.x >> 16) & 3u) | (((g.y >> 16) & 3u) << 2) |
                (((g.z >> 16) & 3u) << 4) | (((g.w >> 16) & 3u) << 6);
  unsigned wl = te * 0x55u, wh = to * 0x55u;   // replicate tag 4x
  return (lo == wl) & (hi == wh);
}
__device__ __forceinline__ uint4 pollg(const unsigned* p, unsigned te, unsigned to) {
  for (;;) {
    uint4 g = cloadg(p);
    if (okg(g, te, to)) return g;
  }
}
__device__ __forceinline__ float tanh_fast(float v) {
  float e = __expf(2.f * v);
  return 1.f - 2.f / (e + 1.f);
}
__device__ __forceinline__ void start_barrier(unsigned* bslots, int wg, int tid, unsigned value) {
  __syncthreads();
  if (tid == 0) cstoreu(&bslots[wg], value);
  if (tid < NWG) {
    while ((int)(cloadu(&bslots[tid]) - value) < 0) __builtin_amdgcn_s_sleep(1);
  }
  __syncthreads();
}
__device__ __forceinline__ unsigned init_word(int slot) {
  if (slot == 0) return 0u;                    // valid step-0 encoding of h=0
  unsigned T = (unsigned)(slot + 7);           // never ≡ slot or slot+8 (mod 16)
  return ((T >> 2) & 3u) << 16 | (T & 3u);
}

__global__ __launch_bounds__(TPB, 2)
void rnn2_q15(const float* __restrict__ x,
              const float* __restrict__ Wih0, const float* __restrict__ Whh0,
              const float* __restrict__ bih0, const float* __restrict__ bhh0,
              const float* __restrict__ Wih1, const float* __restrict__ Whh1,
              const float* __restrict__ bih1, const float* __restrict__ bhh1,
              const float* __restrict__ Wfc,  const float* __restrict__ bfc,
              float* __restrict__ out,
              unsigned* __restrict__ runctr, unsigned* __restrict__ bslots,
              unsigned* __restrict__ h0q, unsigned* __restrict__ h1q)
{
  const int wg   = blockIdx.x;
  const int tid  = threadIdx.x;
  const int wv   = tid >> 6;

  __shared__ float4 lds4[2][1024];   // L0: h0 split [0..511], x [512..575]; L1: h0 [0..511], h1 [512..1023]
  __shared__ float red[8];

  const unsigned runbase = cloadu(runctr);

  if (wg < NWG0) {
    // ---------------- layer 0: 32 rows/WG, 16 threads/row ----------------
    const int cg  = tid & 15;
    const int row = wg * 32 + (tid >> 4);
    float4 wihr[4], whhr[32];
    {
      const float* wr = Wih0 + (size_t)row * I_DIM + (cg << 2);
      #pragma unroll
      for (int k = 0; k < 4; ++k) wihr[k] = ld4(wr + (k << 6));
      const float* wr2 = Whh0 + (size_t)row * H_DIM + (cg << 2);
      #pragma unroll
      for (int k = 0; k < 32; ++k) whhr[k] = ld4(wr2 + (k << 6));
    }
    const float bias = bih0[row] + bhh0[row];
    const unsigned rpar = (unsigned)((tid >> 4) & 1);   // row parity within pair

    if (tid < 128) {   // re-init 8 ring slots of owned u32s (16/WG/slot)
      int sl = tid >> 4; int i = tid & 15;
      cstoreu(&h0q[sl * 1024 + wg * 16 + i], init_word(sl));
    }
    start_barrier(bslots, wg, tid, runbase + 1);

    for (int s = 1; s <= L_SEQ; ++s) {
      const int P = s & 1;
      const int sl = (s - 1) & 7;
      const unsigned te = (unsigned)((s - 1) & 3), to = (unsigned)(((s - 1) >> 2) & 3);
      if (tid < 256) {                 // poll+decode h0_{s-1} granule tid (8 values)
        uint4 g = pollg(h0q + sl * 1024 + (tid << 2), te, to);
        float4 a, b;
        a.x = dec16(g.x); a.y = dec16(g.x >> 16);
        a.z = dec16(g.y); a.w = dec16(g.y >> 16);
        b.x = dec16(g.z); b.y = dec16(g.z >> 16);
        b.z = dec16(g.w); b.w = dec16(g.w >> 16);
        lds4[P][tid] = a;              // f4 2*tid   (even)  -> split pos tid
        lds4[P][256 + tid] = b;        // f4 2*tid+1 (odd)   -> split pos 256+tid
      } else if (tid < 320) {          // stage x_t
        lds4[P][512 + (tid - 256)] = ((const float4*)x)[(size_t)(s - 1) * 64 + (tid - 256)];
      } else if (tid < 448) {          // throttle: all L1 >= s-4 (every 4th step)
        if ((s & 3) == 0 && s > 4) {
          const int s4 = s - 4;
          const unsigned tte = (unsigned)(s4 & 3), tto = (unsigned)((s4 >> 2) & 3);
          const unsigned* tp = h1q + (s4 & 7) * 1024 + (tid - 320) * 8;
          for (;;) {
            unsigned u = cloadu(tp);
            if ((u & 3u) == tte && ((u >> 16) & 3u) == tto) break;
          }
        }
      }
      __syncthreads();

      float acc = 0.f;
      #pragma unroll
      for (int k = 0; k < 4; ++k) {    // x part: f4 idx cg+16k in x region
        float4 h = lds4[P][512 + cg + 16 * k];
        acc += wihr[k].x * h.x + wihr[k].y * h.y + wihr[k].z * h.z + wihr[k].w * h.w;
      }
      #pragma unroll
      for (int k = 0; k < 32; ++k) {   // h part: orig f4 idx cg+16k -> split map
        float4 h = lds4[P][(cg >> 1) + 8 * k + (cg & 1) * 256];
        acc += whhr[k].x * h.x + whhr[k].y * h.y + whhr[k].z * h.z + whhr[k].w * h.w;
      }
      acc += __shfl_xor(acc, 1);
      acc += __shfl_xor(acc, 2);
      acc += __shfl_xor(acc, 4);
      acc += __shfl_xor(acc, 8);

      float hval = tanh_fast(acc + bias);
      unsigned myenc = enc16(hval, rpar ? (unsigned)((s >> 2) & 3) : (unsigned)(s & 3));
      unsigned pairv = myenc | ((unsigned)__shfl_xor((int)myenc, 16) << 16); // valid on even groups
      unsigned otherv = (unsigned)__shfl_xor((int)pairv, 32);                // lane0 <- lane32's pair
      if ((tid & 63) == 0)
        cstore2(h0q + (s & 7) * 1024 + wg * 16 + wv * 2, make_uint2(pairv, otherv));
    }

    if (wg == 0) {
      // FC: sigmoid(h1_8192 . Wfc + bfc); slot 0, tags (0,0).
      // Contents are h1_8184 (hi tag 2 -> rejected) or h1_8192 (valid).
      if (tid < 256) {
        uint4 g = pollg(h1q + (tid << 2), 0u, 0u);
        float4 a, b;
        a.x = dec16(g.x); a.y = dec16(g.x >> 16);
        a.z = dec16(g.y); a.w = dec16(g.y >> 16);
        b.x = dec16(g.z); b.y = dec16(g.z >> 16);
        b.z = dec16(g.w); b.w = dec16(g.w >> 16);
        lds4[0][tid] = a; lds4[0][256 + tid] = b;
      }
      __syncthreads();
      float4 hv = lds4[0][(tid >> 1) + (tid & 1) * 256];
      float4 wf = ((const float4*)Wfc)[tid];
      float pz = hv.x * wf.x + hv.y * wf.y + hv.z * wf.z + hv.w * wf.w;
      #pragma unroll
      for (int m = 1; m < 64; m <<= 1) pz += __shfl_xor(pz, m);
      if ((tid & 63) == 0) red[wv] = pz;
      __syncthreads();
      if (tid == 0) {
        float z = bfc[0];
        #pragma unroll
        for (int w = 0; w < 8; ++w) z += red[w];
        out[0] = 1.f / (1.f + __expf(-z));
        cstoreu(runctr, runbase + 1);
      }
    }
  } else {
    // ---------------- layer 1: 16 rows/WG, 32 threads/row ----------------
    const int cg  = tid & 31;
    const int wgl = wg - NWG0;
    const int row = wgl * 16 + (tid >> 5);
    float4 wihr[16], whhr[16];
    {
      const float* wr = Wih1 + (size_t)row * H_DIM + (cg << 2);
      #pragma unroll
      for (int k = 0; k < 16; ++k) wihr[k] = ld4(wr + (k << 7));
      const float* wr2 = Whh1 + (size_t)row * H_DIM + (cg << 2);
      #pragma unroll
      for (int k = 0; k < 16; ++k) whhr[k] = ld4(wr2 + (k << 7));
    }
    const float bias = bih1[row] + bhh1[row];
    const unsigned rpar = (unsigned)((tid >> 5) & 1);

    if (tid < 64) {    // re-init 8 ring slots of owned u32s (8/WG/slot)
      int sl = tid >> 3; int i = tid & 7;
      cstoreu(&h1q[sl * 1024 + wgl * 8 + i], init_word(sl));
    }
    start_barrier(bslots, wg, tid, runbase + 1);

    for (int t = 1; t <= L_SEQ; ++t) {
      const int P = t & 1;
      if (tid < 256) {                 // poll+decode h0_t
        const unsigned te = (unsigned)(t & 3), to = (unsigned)((t >> 2) & 3);
        uint4 g = pollg(h0q + (t & 7) * 1024 + (tid << 2), te, to);
        float4 a, b;
        a.x = dec16(g.x); a.y = dec16(g.x >> 16);
        a.z = dec16(g.y); a.w = dec16(g.y >> 16);
        b.x = dec16(g.z); b.y = dec16(g.z >> 16);
        b.z = dec16(g.w); b.w = dec16(g.w >> 16);
        lds4[P][tid] = a; lds4[P][256 + tid] = b;
      } else {                         // poll+decode h1_{t-1}
        const int gi = tid - 256;
        const unsigned te = (unsigned)((t - 1) & 3), to = (unsigned)(((t - 1) >> 2) & 3);
        uint4 g = pollg(h1q + ((t - 1) & 7) * 1024 + (gi << 2), te, to);
        float4 a, b;
        a.x = dec16(g.x); a.y = dec16(g.x >> 16);
        a.z = dec16(g.y); a.w = dec16(g.y >> 16);
        b.x = dec16(g.z); b.y = dec16(g.z >> 16);
        b.z = dec16(g.w); b.w = dec16(g.w >> 16);
        lds4[P][512 + gi] = a; lds4[P][768 + gi] = b;
      }
      __syncthreads();

      float acc = 0.f;
      #pragma unroll
      for (int k = 0; k < 16; ++k) {   // h0 part: orig f4 idx cg+32k
        float4 h = lds4[P][(cg >> 1) + 16 * k + (cg & 1) * 256];
        acc += wihr[k].x * h.x + wihr[k].y * h.y + wihr[k].z * h.z + wihr[k].w * h.w;
      }
      #pragma unroll
      for (int k = 0; k < 16; ++k) {   // h1 part
        float4 h = lds4[P][512 + (cg >> 1) + 16 * k + (cg & 1) * 256];
        acc += whhr[k].x * h.x + whhr[k].y * h.y + whhr[k].z * h.z + whhr[k].w * h.w;
      }
      acc += __shfl_xor(acc, 1);
      acc += __shfl_xor(acc, 2);
      acc += __shfl_xor(acc, 4);
      acc += __shfl_xor(acc, 8);
      acc += __shfl_xor(acc, 16);

      float hval = tanh_fast(acc + bias);
      unsigned myenc = enc16(hval, rpar ? (unsigned)((t >> 2) & 3) : (unsigned)(t & 3));
      unsigned pairv = myenc | ((unsigned)__shfl_xor((int)myenc, 32) << 16);  // valid on lanes<32
      if ((tid & 63) == 0)
        cstoreu(h1q + (t & 7) * 1024 + wgl * 8 + wv, pairv);
    }
  }
}

extern "C" void kernel_launch(void* const* d_in, const int* in_sizes, int n_in,
                              void* d_out, int out_size, void* d_ws, size_t ws_size,
                              hipStream_t stream) {
  const float* xx   = (const float*)d_in[0];
  const float* Wih0 = (const float*)d_in[1];
  const float* Whh0 = (const float*)d_in[2];
  const float* bih0 = (const float*)d_in[3];
  const float* bhh0 = (const float*)d_in[4];
  const float* Wih1 = (const float*)d_in[5];
  const float* Whh1 = (const float*)d_in[6];
  const float* bih1 = (const float*)d_in[7];
  const float* bhh1 = (const float*)d_in[8];
  const float* Wfc  = (const float*)d_in[9];
  const float* bfc  = (const float*)d_in[10];

  unsigned* runctr = (unsigned*)d_ws;
  unsigned* bslots = (unsigned*)((char*)d_ws + 256);
  unsigned* h0q    = (unsigned*)((char*)d_ws + 4096);
  unsigned* h1q    = (unsigned*)((char*)d_ws + 4096 + 8 * 1024 * sizeof(unsigned));

  rnn2_q15<<<dim3(NWG), dim3(TPB), 0, stream>>>(
      xx, Wih0, Whh0, bih0, bhh0, Wih1, Whh1, bih1, bhh1, Wfc, bfc,
      (float*)d_out, runctr, bslots, h0q, h1q);
}

// Round 11
// 31937.454 us; speedup vs baseline: 1.5297x; 1.4422x over previous
//
#include <hip/hip_runtime.h>
#include <math.h>

#define L_SEQ 8192
#define I_DIM 256
#define H_DIM 2048
#define NWG0  64          // layer-0: 64 WGs x 32 rows (16 thr/row)
#define NWG1  128         // layer-1: 128 WGs x 16 rows (32 thr/row)
#define NWG   (NWG0 + NWG1)
#define TPB   512

// ws (bytes): [0] runctr | [256..1024) bslots | [4096) h0 ring 8*2048 f32 | [+64K) h1 ring
//
// Base = round-4 (best: 33.1 ms): tagged dataflow, value = h + ctr(step),
// ctr = 4+8*((step>>3)&1), ring depth 8, valid iff |v-ctr|<=1; per-run slot
// re-init; start barrier on monotone runctr. Weight arrays as float4[4]/[32]
// with constant-unrolled indexing (proven AGPR-resident codegen, VGPR=92,
// no scratch -- DO NOT restructure).
//
// Round-11 = round-10 experiment with the asm-input fix (ext_vector_type for
// store payloads; LLVM can't take HIP struct float4 as an asm INPUT):
//  1. s_sleep(1) backoff in all poll loops (cuts futile sc-load pressure).
//  2. Packed publishes: L0 one dwordx4/wave (4 rows, 3 shfl gather),
//     L1 one dwordx2/wave (2 rows, 1 shfl). Per-value tags still absorb
//     partial visibility.
//  3. Throttle every 4th step (want = s-4; margin: overwriting slot s&7 is
//     safe since L1 >= s-4 => consumed h0_{<=s-4}, h1_{<=s-5}; both > s-8),
//     placed after own granule poll (overlapped).

typedef float f32x4 __attribute__((ext_vector_type(4)));
typedef float f32x2 __attribute__((ext_vector_type(2)));

__device__ __forceinline__ void cstore1(float* p, float v) {
  asm volatile("global_store_dword %0, %1, off sc0 sc1" :: "v"(p), "v"(v) : "memory");
}
__device__ __forceinline__ void cstore2f(float* p, float a, float b) {
  f32x2 v; v.x = a; v.y = b;
  asm volatile("global_store_dwordx2 %0, %1, off sc0 sc1" :: "v"(p), "v"(v) : "memory");
}
__device__ __forceinline__ void cstore4f(float* p, float a, float b, float c, float d) {
  f32x4 v; v.x = a; v.y = b; v.z = c; v.w = d;
  asm volatile("global_store_dwordx4 %0, %1, off sc0 sc1" :: "v"(p), "v"(v) : "memory");
}
__device__ __forceinline__ void cstoreu(unsigned* p, unsigned v) {
  asm volatile("global_store_dword %0, %1, off sc0 sc1" :: "v"(p), "v"(v) : "memory");
}
__device__ __forceinline__ float cload1(const float* p) {
  float v;
  asm volatile("global_load_dword %0, %1, off sc0 sc1\n\ts_waitcnt vmcnt(0)"
               : "=v"(v) : "v"(p) : "memory");
  return v;
}
__device__ __forceinline__ unsigned cloadu(const unsigned* p) {
  unsigned v;
  asm volatile("global_load_dword %0, %1, off sc0 sc1\n\ts_waitcnt vmcnt(0)"
               : "=v"(v) : "v"(p) : "memory");
  return v;
}
__device__ __forceinline__ float4 cload4(const float* p) {
  float4 v;
  asm volatile("global_load_dwordx4 %0, %1, off sc0 sc1\n\ts_waitcnt vmcnt(0)"
               : "=v"(v) : "v"(p) : "memory");
  return v;
}
__device__ __forceinline__ void cload4x2(const float* p0, const float* p1, float4& a, float4& b) {
  asm volatile("global_load_dwordx4 %0, %2, off sc0 sc1\n\t"
               "global_load_dwordx4 %1, %3, off sc0 sc1\n\t"
               "s_waitcnt vmcnt(0)"
               : "=&v"(a), "=&v"(b) : "v"(p0), "v"(p1) : "memory");
}
__device__ __forceinline__ float4 ld4(const float* p) {   // weight load, opaque
  float4 v;
  asm volatile("global_load_dwordx4 %0, %1, off\n\ts_waitcnt vmcnt(0)"
               : "=v"(v) : "v"(p) : "memory");
  return v;
}
__device__ __forceinline__ float tagc(int step) {
  return 4.f + 8.f * (float)((step >> 3) & 1);
}
__device__ __forceinline__ bool ok4(float4 v, float c) {
  return __builtin_fabsf(v.x - c) <= 1.f && __builtin_fabsf(v.y - c) <= 1.f &&
         __builtin_fabsf(v.z - c) <= 1.f && __builtin_fabsf(v.w - c) <= 1.f;
}
__device__ __forceinline__ float4 poll4(const float* p, float c) {
  float4 v = cload4(p);
  while (!ok4(v, c)) { __builtin_amdgcn_s_sleep(1); v = cload4(p); }
  return make_float4(v.x - c, v.y - c, v.z - c, v.w - c);
}
__device__ __forceinline__ void poll4x2(const float* p0, float c0,
                                        const float* p1, float c1,
                                        float4& a, float4& b) {
  float4 u, v;
  cload4x2(p0, p1, u, v);
  while (!(ok4(u, c0) && ok4(v, c1))) {
    __builtin_amdgcn_s_sleep(1);
    cload4x2(p0, p1, u, v);
  }
  a = make_float4(u.x - c0, u.y - c0, u.z - c0, u.w - c0);
  b = make_float4(v.x - c1, v.y - c1, v.z - c1, v.w - c1);
}
__device__ __forceinline__ float tanh_fast(float v) {   // exact identity
  float e = __expf(2.f * v);
  return 1.f - 2.f / (e + 1.f);
}
__device__ __forceinline__ void start_barrier(unsigned* bslots, int wg, int tid, unsigned value) {
  __syncthreads();
  if (tid == 0) cstoreu(&bslots[wg], value);
  if (tid < NWG) {
    while ((int)(cloadu(&bslots[tid]) - value) < 0) __builtin_amdgcn_s_sleep(1);
  }
  __syncthreads();
}

__global__ __launch_bounds__(TPB, 2)
void rnn2_backoff(const float* __restrict__ x,
                  const float* __restrict__ Wih0, const float* __restrict__ Whh0,
                  const float* __restrict__ bih0, const float* __restrict__ bhh0,
                  const float* __restrict__ Wih1, const float* __restrict__ Whh1,
                  const float* __restrict__ bih1, const float* __restrict__ bhh1,
                  const float* __restrict__ Wfc,  const float* __restrict__ bfc,
                  float* __restrict__ out,
                  unsigned* __restrict__ runctr, unsigned* __restrict__ bslots,
                  float* __restrict__ h0s, float* __restrict__ h1s)
{
  const int wg  = blockIdx.x;
  const int tid = threadIdx.x;
  const int wv  = tid >> 6;
  __shared__ float4 lds4[2][1024];

  const unsigned runbase = cloadu(runctr);

  if (wg < NWG0) {
    // ---------------- layer 0: 32 rows/WG, 16 threads/row ----------------
    const int cg  = tid & 15;
    const int row = wg * 32 + (tid >> 4);
    float4 wihr[4], whhr[32];
    {
      const float* wr = Wih0 + (size_t)row * I_DIM + (cg << 2);
      #pragma unroll
      for (int k = 0; k < 4; ++k) wihr[k] = ld4(wr + (k << 6));
      const float* wr2 = Whh0 + (size_t)row * H_DIM + (cg << 2);
      #pragma unroll
      for (int k = 0; k < 32; ++k) whhr[k] = ld4(wr2 + (k << 6));
    }
    const float bias = bih0[row] + bhh0[row];

    if (tid < 256) {   // re-init 8 ring slots of owned rows: slot0 = tagged h0_0
      int sl = tid >> 5; int r = wg * 32 + (tid & 31);
      cstore1(&h0s[sl * H_DIM + r], (sl == 0) ? 4.f : 0.f);
    }
    start_barrier(bslots, wg, tid, runbase + 1);

    for (int s = 1; s <= L_SEQ; ++s) {
      const int P = s & 1;
      float4 xv;
      if (tid < 64) xv = ((const float4*)x)[(size_t)(s - 1) * 64 + tid];
      float4 hv = poll4(h0s + ((s - 1) & 7) * H_DIM + (tid << 2), tagc(s - 1));
      lds4[P][64 + tid] = hv;
      if (tid < 64) lds4[P][tid] = xv;
      if ((s & 3) == 0 && s > 4 && tid < NWG1) {
        // throttle (every 4th step, overlapped): all L1 WGs >= s-4
        const float c = tagc(s - 4);
        const float* tp = h1s + ((s - 4) & 7) * H_DIM + (tid << 4);
        while (__builtin_fabsf(cload1(tp) - c) > 1.f) __builtin_amdgcn_s_sleep(1);
      }
      __syncthreads();
      float acc = 0.f;
      #pragma unroll
      for (int k = 0; k < 4; ++k) {
        float4 h = lds4[P][cg + 16 * k];
        acc += wihr[k].x * h.x + wihr[k].y * h.y + wihr[k].z * h.z + wihr[k].w * h.w;
      }
      #pragma unroll
      for (int k = 0; k < 32; ++k) {
        float4 h = lds4[P][64 + cg + 16 * k];
        acc += whhr[k].x * h.x + whhr[k].y * h.y + whhr[k].z * h.z + whhr[k].w * h.w;
      }
      acc += __shfl_xor(acc, 1);
      acc += __shfl_xor(acc, 2);
      acc += __shfl_xor(acc, 4);
      acc += __shfl_xor(acc, 8);
      // packed publish: every lane computes its row's tagged value; lane0 of the
      // wave gathers rows +1,+2,+3 from lanes 16/32/48 and stores one dwordx4.
      float hval = tanh_fast(acc + bias) + tagc(s);
      float g1 = __shfl(hval, 16);
      float g2 = __shfl(hval, 32);
      float g3 = __shfl(hval, 48);
      if ((tid & 63) == 0)
        cstore4f(h0s + (s & 7) * H_DIM + wg * 32 + wv * 4, hval, g1, g2, g3);
    }

    if (wg == 0) {
      // FC: sigmoid(h1_8192 . Wfc + bfc); slot 8192&7 = 0, ctr 4.
      // Throttle at s=8192 guaranteed L1 >= 8188 => slot 0 holds 8184 (ctr 12,
      // rejected) or 8192 (ctr 4, accepted).
      float4 hv = poll4(h1s + (tid << 2), tagc(L_SEQ));
      float4 wf = ((const float4*)Wfc)[tid];
      float pz = hv.x * wf.x + hv.y * wf.y + hv.z * wf.z + hv.w * wf.w;
      #pragma unroll
      for (int m = 1; m < 64; m <<= 1) pz += __shfl_xor(pz, m);
      float* red = (float*)&lds4[0][0];
      __syncthreads();
      if ((tid & 63) == 0) red[wv] = pz;
      __syncthreads();
      if (tid == 0) {
        float z = bfc[0];
        #pragma unroll
        for (int w = 0; w < 8; ++w) z += red[w];
        out[0] = 1.f / (1.f + __expf(-z));
        cstoreu(runctr, runbase + 1);
      }
    }
  } else {
    // ---------------- layer 1: 16 rows/WG, 32 threads/row ----------------
    const int cg  = tid & 31;
    const int wgl = wg - NWG0;
    const int row = wgl * 16 + (tid >> 5);
    float4 wihr[16], whhr[16];
    {
      const float* wr = Wih1 + (size_t)row * H_DIM + (cg << 2);
      #pragma unroll
      for (int k = 0; k < 16; ++k) wihr[k] = ld4(wr + (k << 7));
      const float* wr2 = Whh1 + (size_t)row * H_DIM + (cg << 2);
      #pragma unroll
      for (int k = 0; k < 16; ++k) whhr[k] = ld4(wr2 + (k << 7));
    }
    const float bias = bih1[row] + bhh1[row];

    if (tid < 128) {   // re-init 8 ring slots of owned rows: slot0 = tagged h1_0
      int sl = tid >> 4; int r = wgl * 16 + (tid & 15);
      cstore1(&h1s[sl * H_DIM + r], (sl == 0) ? 4.f : 0.f);
    }
    start_barrier(bslots, wg, tid, runbase + 1);

    for (int t = 1; t <= L_SEQ; ++t) {
      const int P = t & 1;
      float4 a, b;
      poll4x2(h0s + (t & 7) * H_DIM + (tid << 2), tagc(t),
              h1s + ((t - 1) & 7) * H_DIM + (tid << 2), tagc(t - 1), a, b);
      lds4[P][tid] = a;
      lds4[P][512 + tid] = b;
      __syncthreads();
      float acc = 0.f;
      #pragma unroll
      for (int k = 0; k < 16; ++k) {
        float4 h = lds4[P][cg + 32 * k];
        acc += wihr[k].x * h.x + wihr[k].y * h.y + wihr[k].z * h.z + wihr[k].w * h.w;
      }
      #pragma unroll
      for (int k = 0; k < 16; ++k) {
        float4 h = lds4[P][512 + cg + 32 * k];
        acc += whhr[k].x * h.x + whhr[k].y * h.y + whhr[k].z * h.z + whhr[k].w * h.w;
      }
      acc += __shfl_xor(acc, 1);
      acc += __shfl_xor(acc, 2);
      acc += __shfl_xor(acc, 4);
      acc += __shfl_xor(acc, 8);
      acc += __shfl_xor(acc, 16);
      // packed publish: lane0 of the wave stores rows {r0, r0+1} as one dwordx2.
      float hval = tanh_fast(acc + bias) + tagc(t);
      float g1 = __shfl(hval, 32);
      if ((tid & 63) == 0)
        cstore2f(h1s + (t & 7) * H_DIM + wgl * 16 + wv * 2, hval, g1);
    }
  }
}

extern "C" void kernel_launch(void* const* d_in, const int* in_sizes, int n_in,
                              void* d_out, int out_size, void* d_ws, size_t ws_size,
                              hipStream_t stream) {
  const float* xx   = (const float*)d_in[0];
  const float* Wih0 = (const float*)d_in[1];
  const float* Whh0 = (const float*)d_in[2];
  const float* bih0 = (const float*)d_in[3];
  const float* bhh0 = (const float*)d_in[4];
  const float* Wih1 = (const float*)d_in[5];
  const float* Whh1 = (const float*)d_in[6];
  const float* bih1 = (const float*)d_in[7];
  const float* bhh1 = (const float*)d_in[8];
  const float* Wfc  = (const float*)d_in[9];
  const float* bfc  = (const float*)d_in[10];

  unsigned* runctr = (unsigned*)d_ws;
  unsigned* bslots = (unsigned*)((char*)d_ws + 256);
  float* h0s       = (float*)((char*)d_ws + 4096);
  float* h1s       = (float*)((char*)d_ws + 4096 + 8 * H_DIM * sizeof(float));

  rnn2_backoff<<<dim3(NWG), dim3(TPB), 0, stream>>>(
      xx, Wih0, Whh0, bih0, bhh0, Wih1, Whh1, bih1, bhh1, Wfc, bfc,
      (float*)d_out, runctr, bslots, h0s, h1s);
}

// Round 12
// 24729.758 us; speedup vs baseline: 1.9755x; 1.2915x over previous
//
#include <hip/hip_runtime.h>
#include <math.h>

#define L_SEQ 8192
#define I_DIM 256
#define H_DIM 2048
#define NWG0  64          // layer-0: 64 WGs x 32 rows (16 thr/row)
#define NWG1  128         // layer-1: 128 WGs x 16 rows (32 thr/row)
#define NWG   (NWG0 + NWG1)
#define TPB   512
#define RD    16          // h ring depth (was 8)
#define RM    (RD - 1)
#define TLAG  11          // L0 throttle lag (checked every 4th step)

// ws (bytes): [0] runctr | [256..1024) bslots | [4096) h0 ring 16*2048 f32
//             | [4096+128K) h1 ring 16*2048 f32
//
// Base = round-11 (best: 31.9 ms). Tagged dataflow: published value =
// h + ctr(step), ctr = 4+8*((step>>4)&1), ring depth 16, valid iff |v-ctr|<=1;
// per-run slot re-init (slot0 = tagged h_0, slots 1..15 = 0.0f invalid);
// 0xAA poison (-3e-13) and 0.0f fail both windows [3,5]/[11,13]. Start barrier
// on monotone runctr. Weight arrays float4[4]/[32]/[16] constant-unrolled
// (proven no-scratch codegen, VGPR=92 -- DO NOT restructure).
//
// Round-12 diffs:
//  1. Ring 16 + throttle lag 11 every 4th step: L0 may run up to 11 ahead of
//     L1 (was 4) -- absorbs inter-layer jitter. Safety: L0 writing slot s&15
//     kills h0_{s-16}; throttle gives L1 >= s-3-11 = s-14 > s-16 (margin 2).
//     L0 peers are >= s-1 (validated h0_{s-1} fully). Tag aliasing needs
//     lag >= 32: max spread ~15. FC: last throttle (s=8192) => L1 >= 8181;
//     h1 slot 0 then holds 8176 (tag 1, rejected) or 8192 (tag 0, accepted).
//  2. L1 split-dot: poll h0_t (always ready at lag <= 11) + ih-dot FIRST,
//     then poll h1_{t-1} -- peers' h1 stores get ~700 cy extra to land, and
//     only the hh half of the compute sits after the critical detect.

typedef float f32x4 __attribute__((ext_vector_type(4)));
typedef float f32x2 __attribute__((ext_vector_type(2)));

__device__ __forceinline__ void cstore1(float* p, float v) {
  asm volatile("global_store_dword %0, %1, off sc0 sc1" :: "v"(p), "v"(v) : "memory");
}
__device__ __forceinline__ void cstore2f(float* p, float a, float b) {
  f32x2 v; v.x = a; v.y = b;
  asm volatile("global_store_dwordx2 %0, %1, off sc0 sc1" :: "v"(p), "v"(v) : "memory");
}
__device__ __forceinline__ void cstore4f(float* p, float a, float b, float c, float d) {
  f32x4 v; v.x = a; v.y = b; v.z = c; v.w = d;
  asm volatile("global_store_dwordx4 %0, %1, off sc0 sc1" :: "v"(p), "v"(v) : "memory");
}
__device__ __forceinline__ void cstoreu(unsigned* p, unsigned v) {
  asm volatile("global_store_dword %0, %1, off sc0 sc1" :: "v"(p), "v"(v) : "memory");
}
__device__ __forceinline__ float cload1(const float* p) {
  float v;
  asm volatile("global_load_dword %0, %1, off sc0 sc1\n\ts_waitcnt vmcnt(0)"
               : "=v"(v) : "v"(p) : "memory");
  return v;
}
__device__ __forceinline__ unsigned cloadu(const unsigned* p) {
  unsigned v;
  asm volatile("global_load_dword %0, %1, off sc0 sc1\n\ts_waitcnt vmcnt(0)"
               : "=v"(v) : "v"(p) : "memory");
  return v;
}
__device__ __forceinline__ float4 cload4(const float* p) {
  float4 v;
  asm volatile("global_load_dwordx4 %0, %1, off sc0 sc1\n\ts_waitcnt vmcnt(0)"
               : "=v"(v) : "v"(p) : "memory");
  return v;
}
__device__ __forceinline__ float4 ld4(const float* p) {   // weight load, opaque
  float4 v;
  asm volatile("global_load_dwordx4 %0, %1, off\n\ts_waitcnt vmcnt(0)"
               : "=v"(v) : "v"(p) : "memory");
  return v;
}
__device__ __forceinline__ float tagc(int step) {
  return 4.f + 8.f * (float)((step >> 4) & 1);
}
__device__ __forceinline__ bool ok4(float4 v, float c) {
  return __builtin_fabsf(v.x - c) <= 1.f && __builtin_fabsf(v.y - c) <= 1.f &&
         __builtin_fabsf(v.z - c) <= 1.f && __builtin_fabsf(v.w - c) <= 1.f;
}
__device__ __forceinline__ float4 poll4(const float* p, float c) {
  float4 v = cload4(p);
  while (!ok4(v, c)) { __builtin_amdgcn_s_sleep(1); v = cload4(p); }
  return make_float4(v.x - c, v.y - c, v.z - c, v.w - c);
}
__device__ __forceinline__ float tanh_fast(float v) {   // exact identity
  float e = __expf(2.f * v);
  return 1.f - 2.f / (e + 1.f);
}
__device__ __forceinline__ void start_barrier(unsigned* bslots, int wg, int tid, unsigned value) {
  __syncthreads();
  if (tid == 0) cstoreu(&bslots[wg], value);
  if (tid < NWG) {
    while ((int)(cloadu(&bslots[tid]) - value) < 0) __builtin_amdgcn_s_sleep(1);
  }
  __syncthreads();
}

__global__ __launch_bounds__(TPB, 2)
void rnn2_ring16(const float* __restrict__ x,
                 const float* __restrict__ Wih0, const float* __restrict__ Whh0,
                 const float* __restrict__ bih0, const float* __restrict__ bhh0,
                 const float* __restrict__ Wih1, const float* __restrict__ Whh1,
                 const float* __restrict__ bih1, const float* __restrict__ bhh1,
                 const float* __restrict__ Wfc,  const float* __restrict__ bfc,
                 float* __restrict__ out,
                 unsigned* __restrict__ runctr, unsigned* __restrict__ bslots,
                 float* __restrict__ h0s, float* __restrict__ h1s)
{
  const int wg  = blockIdx.x;
  const int tid = threadIdx.x;
  const int wv  = tid >> 6;
  __shared__ float4 lds4[2][1024];

  const unsigned runbase = cloadu(runctr);

  if (wg < NWG0) {
    // ---------------- layer 0: 32 rows/WG, 16 threads/row ----------------
    const int cg  = tid & 15;
    const int row = wg * 32 + (tid >> 4);
    float4 wihr[4], whhr[32];
    {
      const float* wr = Wih0 + (size_t)row * I_DIM + (cg << 2);
      #pragma unroll
      for (int k = 0; k < 4; ++k) wihr[k] = ld4(wr + (k << 6));
      const float* wr2 = Whh0 + (size_t)row * H_DIM + (cg << 2);
      #pragma unroll
      for (int k = 0; k < 32; ++k) whhr[k] = ld4(wr2 + (k << 6));
    }
    const float bias = bih0[row] + bhh0[row];

    {   // re-init all 16 ring slots of owned rows: slot0 = tagged h0_0 (=4.0)
      int sl = tid >> 5; int r = wg * 32 + (tid & 31);
      cstore1(&h0s[sl * H_DIM + r], (sl == 0) ? 4.f : 0.f);
    }
    start_barrier(bslots, wg, tid, runbase + 1);

    for (int s = 1; s <= L_SEQ; ++s) {
      const int P = s & 1;
      float4 xv;
      if (tid < 64) xv = ((const float4*)x)[(size_t)(s - 1) * 64 + tid];
      float4 hv = poll4(h0s + ((s - 1) & RM) * H_DIM + (tid << 2), tagc(s - 1));
      lds4[P][64 + tid] = hv;
      if (tid < 64) lds4[P][tid] = xv;
      if ((s & 3) == 0 && s >= 12 && tid < NWG1) {
        // throttle (every 4th step, overlapped): all L1 WGs >= s-11
        const float c = tagc(s - TLAG);
        const float* tp = h1s + ((s - TLAG) & RM) * H_DIM + (tid << 4);
        while (__builtin_fabsf(cload1(tp) - c) > 1.f) __builtin_amdgcn_s_sleep(1);
      }
      __syncthreads();
      float acc = 0.f;
      #pragma unroll
      for (int k = 0; k < 4; ++k) {
        float4 h = lds4[P][cg + 16 * k];
        acc += wihr[k].x * h.x + wihr[k].y * h.y + wihr[k].z * h.z + wihr[k].w * h.w;
      }
      #pragma unroll
      for (int k = 0; k < 32; ++k) {
        float4 h = lds4[P][64 + cg + 16 * k];
        acc += whhr[k].x * h.x + whhr[k].y * h.y + whhr[k].z * h.z + whhr[k].w * h.w;
      }
      acc += __shfl_xor(acc, 1);
      acc += __shfl_xor(acc, 2);
      acc += __shfl_xor(acc, 4);
      acc += __shfl_xor(acc, 8);
      // packed publish: one dwordx4 per wave (rows wv*4 .. wv*4+3)
      float hval = tanh_fast(acc + bias) + tagc(s);
      float g1 = __shfl(hval, 16);
      float g2 = __shfl(hval, 32);
      float g3 = __shfl(hval, 48);
      if ((tid & 63) == 0)
        cstore4f(h0s + (s & RM) * H_DIM + wg * 32 + wv * 4, hval, g1, g2, g3);
    }

    if (wg == 0) {
      // FC: sigmoid(h1_8192 . Wfc + bfc); slot 8192&15 = 0, ctr 4.
      // Last throttle (s=8192) gave L1 >= 8181 => slot 0 holds 8176 (tag 1,
      // rejected) or 8192 (tag 0, accepted); init value long overwritten.
      float4 hv = poll4(h1s + (tid << 2), tagc(L_SEQ));
      float4 wf = ((const float4*)Wfc)[tid];
      float pz = hv.x * wf.x + hv.y * wf.y + hv.z * wf.z + hv.w * wf.w;
      #pragma unroll
      for (int m = 1; m < 64; m <<= 1) pz += __shfl_xor(pz, m);
      float* red = (float*)&lds4[0][0];
      __syncthreads();
      if ((tid & 63) == 0) red[wv] = pz;
      __syncthreads();
      if (tid == 0) {
        float z = bfc[0];
        #pragma unroll
        for (int w = 0; w < 8; ++w) z += red[w];
        out[0] = 1.f / (1.f + __expf(-z));
        cstoreu(runctr, runbase + 1);
      }
    }
  } else {
    // ---------------- layer 1: 16 rows/WG, 32 threads/row, split-dot ----------------
    const int cg  = tid & 31;
    const int wgl = wg - NWG0;
    const int row = wgl * 16 + (tid >> 5);
    float4 wihr[16], whhr[16];
    {
      const float* wr = Wih1 + (size_t)row * H_DIM + (cg << 2);
      #pragma unroll
      for (int k = 0; k < 16; ++k) wihr[k] = ld4(wr + (k << 7));
      const float* wr2 = Whh1 + (size_t)row * H_DIM + (cg << 2);
      #pragma unroll
      for (int k = 0; k < 16; ++k) whhr[k] = ld4(wr2 + (k << 7));
    }
    const float bias = bih1[row] + bhh1[row];

    if (tid < 256) {   // re-init all 16 ring slots of owned rows
      int sl = tid >> 4; int r = wgl * 16 + (tid & 15);
      cstore1(&h1s[sl * H_DIM + r], (sl == 0) ? 4.f : 0.f);
    }
    start_barrier(bslots, wg, tid, runbase + 1);

    for (int t = 1; t <= L_SEQ; ++t) {
      const int P = t & 1;
      // phase A: h0_t (L0 runs up to 11 ahead -- effectively always ready)
      float4 a = poll4(h0s + (t & RM) * H_DIM + (tid << 2), tagc(t));
      lds4[P][tid] = a;
      __syncthreads();
      float acc = 0.f;
      #pragma unroll
      for (int k = 0; k < 16; ++k) {
        float4 h = lds4[P][cg + 32 * k];
        acc += wihr[k].x * h.x + wihr[k].y * h.y + wihr[k].z * h.z + wihr[k].w * h.w;
      }
      // phase B: h1_{t-1} -- the critical detect; peers' stores had ~ih-dot
      // duration to become visible.
      float4 b = poll4(h1s + ((t - 1) & RM) * H_DIM + (tid << 2), tagc(t - 1));
      lds4[P][512 + tid] = b;
      __syncthreads();
      #pragma unroll
      for (int k = 0; k < 16; ++k) {
        float4 h = lds4[P][512 + cg + 32 * k];
        acc += whhr[k].x * h.x + whhr[k].y * h.y + whhr[k].z * h.z + whhr[k].w * h.w;
      }
      acc += __shfl_xor(acc, 1);
      acc += __shfl_xor(acc, 2);
      acc += __shfl_xor(acc, 4);
      acc += __shfl_xor(acc, 8);
      acc += __shfl_xor(acc, 16);
      // packed publish: one dwordx2 per wave (rows wv*2, wv*2+1)
      float hval = tanh_fast(acc + bias) + tagc(t);
      float g1 = __shfl(hval, 32);
      if ((tid & 63) == 0)
        cstore2f(h1s + (t & RM) * H_DIM + wgl * 16 + wv * 2, hval, g1);
    }
  }
}

extern "C" void kernel_launch(void* const* d_in, const int* in_sizes, int n_in,
                              void* d_out, int out_size, void* d_ws, size_t ws_size,
                              hipStream_t stream) {
  const float* xx   = (const float*)d_in[0];
  const float* Wih0 = (const float*)d_in[1];
  const float* Whh0 = (const float*)d_in[2];
  const float* bih0 = (const float*)d_in[3];
  const float* bhh0 = (const float*)d_in[4];
  const float* Wih1 = (const float*)d_in[5];
  const float* Whh1 = (const float*)d_in[6];
  const float* bih1 = (const float*)d_in[7];
  const float* bhh1 = (const float*)d_in[8];
  const float* Wfc  = (const float*)d_in[9];
  const float* bfc  = (const float*)d_in[10];

  unsigned* runctr = (unsigned*)d_ws;
  unsigned* bslots = (unsigned*)((char*)d_ws + 256);
  float* h0s       = (float*)((char*)d_ws + 4096);
  float* h1s       = (float*)((char*)d_ws + 4096 + RD * H_DIM * sizeof(float));

  rnn2_ring16<<<dim3(NWG), dim3(TPB), 0, stream>>>(
      xx, Wih0, Whh0, bih0, bhh0, Wih1, Whh1, bih1, bhh1, Wfc, bfc,
      (float*)d_out, runctr, bslots, h0s, h1s);
}